// Round 9
// baseline (3544.352 us; speedup 1.0000x reference)
//
#include <hip/hip_runtime.h>
#include <math.h>

#define BATCH 32
#define TFRAMES 1024
#define NBINS 257
#define NFFT 512
#define HOP 160
#define LOUT 163680
#define XPLEN 164192
#define NITER 32
#define FPW 4                        // frames per wave
#define WSTRIDE (FPW*HOP)            // 640
#define BSTRIDE (2*WSTRIDE)          // 1280 (block = 2 waves = 8 frames)
#define HALO (NFFT-HOP)              // 352
#define WSPAN (WSTRIDE+HALO)         // 992  per-wave OLA span
#define SPAN (BSTRIDE+HALO)          // 1632 per-block OLA span
#define NBLK 128                     // blocks per batch row
#define SLOT SPAN
#define SB ((size_t)NBLK*SLOT)
#define SBUF ((size_t)BATCH*SB)

#define P(i) ((i) + ((i) >> 5))      // LDS pad: 2-way max on stride-1/64 patterns

__device__ __forceinline__ float cosr(float x){ return __builtin_amdgcn_cosf(x); }
__device__ __forceinline__ float sinr(float x){ return __builtin_amdgcn_sinf(x); }
__device__ __forceinline__ void wsync(){
    __builtin_amdgcn_fence(__ATOMIC_SEQ_CST, "wavefront");
    __builtin_amdgcn_wave_barrier();
}

struct Tw { float c1,s1,c2,s2,c3,s3; };
__device__ __forceinline__ Tw twset(float x){
    Tw t; float c=cosr(x), s=sinr(x);
    t.c1=c; t.s1=s;
    t.c2=c*c-s*s; t.s2=2.f*c*s;
    t.c3=t.c2*c-t.s2*s; t.s3=t.c2*s+t.s2*c;
    return t;
}

template<int SIGN, bool TWID>
__device__ __forceinline__ void bfly4(const float xr[4], const float xi[4],
                                      const Tw& t, float yr[4], float yi[4]){
    constexpr float SG = (SIGN>0)?1.f:-1.f;
    float apc_r=xr[0]+xr[2], apc_i=xi[0]+xi[2];
    float amc_r=xr[0]-xr[2], amc_i=xi[0]-xi[2];
    float bpd_r=xr[1]+xr[3], bpd_i=xi[1]+xi[3];
    float bmd_r=xr[1]-xr[3], bmd_i=xi[1]-xi[3];
    yr[0]=apc_r+bpd_r; yi[0]=apc_i+bpd_i;
    float u2r=apc_r-bpd_r, u2i=apc_i-bpd_i;
    float u1r=amc_r-SG*bmd_i, u1i=amc_i+SG*bmd_r;
    float u3r=amc_r+SG*bmd_i, u3i=amc_i-SG*bmd_r;
    if (TWID){
        float s1=SG*t.s1, s2=SG*t.s2, s3=SG*t.s3;
        yr[1]=t.c1*u1r-s1*u1i; yi[1]=t.c1*u1i+s1*u1r;
        yr[2]=t.c2*u2r-s2*u2i; yi[2]=t.c2*u2i+s2*u2r;
        yr[3]=t.c3*u3r-s3*u3i; yi[3]=t.c3*u3i+s3*u3r;
    } else {
        yr[1]=u1r; yi[1]=u1i; yr[2]=u2r; yi[2]=u2i; yr[3]=u3r; yi[3]=u3i;
    }
}

// single-frame LDS Stockham (k_inv0s only — runs once)
template<int SIGN>
__device__ __forceinline__ void fft256reg(float xr[4], float xi[4],
                                          float* br, float* bi,
                                          const Tw& tw0, const Tw& tw1, const Tw& tw2,
                                          int lane){
    float yr[4], yi[4], ar[4], ai[4];
    bfly4<SIGN,true>(xr, xi, tw0, yr, yi);
    { int o = 4*lane;
#pragma unroll
      for (int c=0;c<4;++c){ br[P(o+c)]=yr[c]; bi[P(o+c)]=yi[c]; } }
    wsync();
#pragma unroll
    for (int c=0;c<4;++c){ ar[c]=br[P(lane+64*c)]; ai[c]=bi[P(lane+64*c)]; }
    wsync();
    bfly4<SIGN,true>(ar, ai, tw1, yr, yi);
    { int o = (lane&3) + 16*(lane>>2);
#pragma unroll
      for (int c=0;c<4;++c){ br[P(o+4*c)]=yr[c]; bi[P(o+4*c)]=yi[c]; } }
    wsync();
#pragma unroll
    for (int c=0;c<4;++c){ ar[c]=br[P(lane+64*c)]; ai[c]=bi[P(lane+64*c)]; }
    wsync();
    bfly4<SIGN,true>(ar, ai, tw2, yr, yi);
    { int o = (lane&15) + 64*(lane>>4);
#pragma unroll
      for (int c=0;c<4;++c){ br[P(o+16*c)]=yr[c]; bi[P(o+16*c)]=yi[c]; } }
    wsync();
#pragma unroll
    for (int c=0;c<4;++c){ ar[c]=br[P(lane+64*c)]; ai[c]=bi[P(lane+64*c)]; }
    wsync();
    bfly4<SIGN,false>(ar, ai, tw0, xr, xi);
}

// two-frame interleaved Stockham: identical index math, shared fences.
template<int SIGN>
__device__ __forceinline__ void fft256_x2(float x0r[4], float x0i[4], float* b0r, float* b0i,
                                          float x1r[4], float x1i[4], float* b1r, float* b1i,
                                          const Tw& tw0, const Tw& tw1, const Tw& tw2,
                                          int lane){
    float y0r[4], y0i[4], y1r[4], y1i[4];
    float a0r[4], a0i[4], a1r[4], a1i[4];
    bfly4<SIGN,true>(x0r, x0i, tw0, y0r, y0i);
    bfly4<SIGN,true>(x1r, x1i, tw0, y1r, y1i);
    { int o = 4*lane;
#pragma unroll
      for (int c=0;c<4;++c){ b0r[P(o+c)]=y0r[c]; b0i[P(o+c)]=y0i[c];
                             b1r[P(o+c)]=y1r[c]; b1i[P(o+c)]=y1i[c]; } }
    wsync();
#pragma unroll
    for (int c=0;c<4;++c){ int u=P(lane+64*c);
        a0r[c]=b0r[u]; a0i[c]=b0i[u]; a1r[c]=b1r[u]; a1i[c]=b1i[u]; }
    wsync();
    bfly4<SIGN,true>(a0r, a0i, tw1, y0r, y0i);
    bfly4<SIGN,true>(a1r, a1i, tw1, y1r, y1i);
    { int o = (lane&3) + 16*(lane>>2);
#pragma unroll
      for (int c=0;c<4;++c){ int u=P(o+4*c);
          b0r[u]=y0r[c]; b0i[u]=y0i[c]; b1r[u]=y1r[c]; b1i[u]=y1i[c]; } }
    wsync();
#pragma unroll
    for (int c=0;c<4;++c){ int u=P(lane+64*c);
        a0r[c]=b0r[u]; a0i[c]=b0i[u]; a1r[c]=b1r[u]; a1i[c]=b1i[u]; }
    wsync();
    bfly4<SIGN,true>(a0r, a0i, tw2, y0r, y0i);
    bfly4<SIGN,true>(a1r, a1i, tw2, y1r, y1i);
    { int o = (lane&15) + 64*(lane>>4);
#pragma unroll
      for (int c=0;c<4;++c){ int u=P(o+16*c);
          b0r[u]=y0r[c]; b0i[u]=y0i[c]; b1r[u]=y1r[c]; b1i[u]=y1i[c]; } }
    wsync();
#pragma unroll
    for (int c=0;c<4;++c){ int u=P(lane+64*c);
        a0r[c]=b0r[u]; a0i[c]=b0i[u]; a1r[c]=b1r[u]; a1i[c]=b1i[u]; }
    wsync();
    bfly4<SIGN,false>(a0r, a0i, tw0, x0r, x0i);
    bfly4<SIGN,false>(a1r, a1i, tw0, x1r, x1i);
}

// ============================================================
__global__ __launch_bounds__(256) void k_init(const float* __restrict__ win,
                                              float* __restrict__ wsqi){
    int i = blockIdx.x*256 + threadIdx.x;
    if (i < XPLEN){
        int n = i;
        int tmax = n / HOP; if (tmax > TFRAMES-1) tmax = TFRAMES-1;
        int tmin = (n - (NFFT-1) + (HOP-1)) / HOP; if (tmin < 0) tmin = 0;
        float acc = 0.f;
        for (int t = tmin; t <= tmax; ++t){ float w = win[n - t*HOP]; acc += w*w; }
        wsqi[i] = 1.0f / (acc > 1e-11f ? acc : 1.0f);
    }
}

// slot-reconstructed signal reads
__device__ __forceinline__ float xs(const float* __restrict__ Sb,
                                    const float* __restrict__ wsq, int p){
    int bxp = p / BSTRIDE, r = p - bxp*BSTRIDE;
    float a = 0.f;
    if (bxp < NBLK) a = Sb[(size_t)bxp*SLOT + r];
    if (r < HALO && bxp > 0) a += Sb[(size_t)(bxp-1)*SLOT + BSTRIDE + r];
    return a * wsq[p];
}
__device__ __forceinline__ float2 xs2(const float* __restrict__ Sb,
                                      const float* __restrict__ wsq, int p){ // p even
    int bxp = p / BSTRIDE, r = p - bxp*BSTRIDE;
    float2 acc = make_float2(0.f, 0.f);
    if (bxp < NBLK) acc = *(const float2*)(Sb + (size_t)bxp*SLOT + r);
    if (r < HALO && bxp > 0){
        float2 h = *(const float2*)(Sb + (size_t)(bxp-1)*SLOT + BSTRIDE + r);
        acc.x += h.x; acc.y += h.y;
    }
    float2 q = *(const float2*)(wsq + p);
    return make_float2(acc.x*q.x, acc.y*q.y);
}

// legacy inverse tail for k_inv0s
__device__ __forceinline__ void inv_accum(float pr[4], float pi[4],
                                          float* br, float* bi,
                                          const Tw& tw0, const Tw& tw1, const Tw& tw2,
                                          const float wA[4], const float wB[4],
                                          int lane, int f, float2* sa2){
    fft256reg<+1>(pr, pi, br, bi, tw0, tw1, tw2, lane);
    constexpr float SC = 1.f/256.f;
    int base2 = f*(HOP/2);
#pragma unroll
    for (int c=0;c<4;++c){
        int u = base2 + lane + 64*c;
        float2 v = sa2[u];
        v.x += pr[c]*wA[c]*SC;
        v.y += pi[c]*wB[c]*SC;
        sa2[u] = v;
    }
    wsync();
}

__device__ __forceinline__ void slot_store(float* __restrict__ Sw, int b, int bx,
                                           const float* s0, const float* s1, int tid){
    float2* slot2 = (float2*)(Sw + ((size_t)b*NBLK + bx)*SLOT);
    const float2* s0_2 = (const float2*)s0;
    const float2* s1_2 = (const float2*)s1;
#pragma unroll
    for (int j=0;j<7;++j){
        int u = tid + 128*j;
        if (u < SPAN/2){
            float2 v = make_float2(0.f, 0.f);
            if (u < WSPAN/2) v = s0_2[u];
            if (u >= WSTRIDE/2){
                float2 w1 = s1_2[u - WSTRIDE/2];
                v.x += w1.x; v.y += w1.y;
            }
            slot2[u] = v;
        }
    }
}

// frame load (r6-verbatim logic)
__device__ __forceinline__ void load_frame(const float* __restrict__ Sb,
                                           const float* __restrict__ wsq,
                                           int t, int lane,
                                           const float wA[4], const float wB[4],
                                           float fr[4], float fi[4]){
    bool edge = (t < 2) | (t >= TFRAMES-2);
    if (!edge){
        int pb = t*HOP;
#pragma unroll
        for (int c=0;c<4;++c){
            int p = pb + 2*(lane + 64*c);
            float2 v = xs2(Sb, wsq, p);
            fr[c] = v.x*wA[c];
            fi[c] = v.y*wB[c];
        }
    } else {
#pragma unroll
        for (int c=0;c<4;++c){
            int m = lane + 64*c;
            int p0 = t*HOP + 2*m, p1 = p0+1;
            int n0 = (p0<256)?(512-p0):((p0>=LOUT+256)?(2*LOUT+510-p0):p0);
            int n1 = (p1<256)?(512-p1):((p1>=LOUT+256)?(2*LOUT+510-p1):p1);
            fr[c] = xs(Sb, wsq, n0)*wA[c];
            fi[c] = xs(Sb, wsq, n1)*wB[c];
        }
    }
}

// spectral projection for one frame (r6-verbatim math)
__device__ __forceinline__ void spectral(const float fr[4], const float fi[4],
                                         const float yr[4], const float yi[4],
                                         const float* __restrict__ magp,
                                         const float twc[4], const float tws[4],
                                         int lane, float pr[4], float pi[4]){
#pragma unroll
    for (int c=0;c<4;++c){
        int k = lane + 64*c;
        float zr = fr[c], zi = fi[c];
        float Xer = 0.5f*(zr+yr[c]), Xei = 0.5f*(zi-yi[c]);
        float Dr = zr-yr[c], Di = zi+yi[c];
        float Xor = 0.5f*Di, Xoi = -0.5f*Dr;
        float Or = twc[c]*Xor + tws[c]*Xoi;
        float Oi = twc[c]*Xoi - tws[c]*Xor;
        float X1r = Xer + Or, X1i = Xei + Oi;
        float X2r = Xer - Or, X2i = Oi - Xei;
        float q1 = X1r*X1r + X1i*X1i;
        bool ok1 = q1 > 1e-30f;
        float v1 = ok1 ? __builtin_amdgcn_rsqf(q1) : 0.f;
        float c1 = ok1 ? X1r*v1 : 1.f, s1 = X1i*v1;
        float q2 = X2r*X2r + X2i*X2i;
        bool ok2 = q2 > 1e-30f;
        float v2 = ok2 ? __builtin_amdgcn_rsqf(q2) : 0.f;
        float c2 = ok2 ? X2r*v2 : 1.f, s2 = X2i*v2;
        float m1 = magp[k], m2 = magp[256-k];
        float S1r = m1*c1, S1i = m1*s1;
        float S2r = m2*c2, S2i = m2*s2;
        float Aer = 0.5f*(S1r+S2r), Aei = 0.5f*(S1i-S2i);
        float Er = S1r - S2r, Ei = S1i + S2i;
        float Bor = 0.5f*(twc[c]*Er - tws[c]*Ei);
        float Boi = 0.5f*(twc[c]*Ei + tws[c]*Er);
        pr[c] = Aer - Boi;
        pi[c] = Aei + Bor;
    }
}

// ============================================================
// k_gl: one Griffin-Lim iteration. block = 2 waves x 4 frames;
// frames processed in interleaved pairs (2x ILP per fence region).
// waves_per_eu(4,4): pin allocator budget to 128 VGPRs — r8's allocator
// targeted 8 waves/EU (64 VGPRs) and spilled ~300 MB/dispatch to scratch.
// ============================================================
__global__ __launch_bounds__(128)
__attribute__((amdgpu_waves_per_eu(4,4)))
void k_gl(const float* __restrict__ Sr,
          float* __restrict__ Sw,
          const float* __restrict__ mag,
          const float* __restrict__ win,
          const float* __restrict__ wsq){
    __shared__ __align__(16) float sacc[2][WSPAN];
    __shared__ __align__(16) float FRA[2][272], FIA[2][272];
    __shared__ __align__(16) float FRB[2][272], FIB[2][272];
    int tid = threadIdx.x, w = tid>>6, lane = tid&63;
    int b = blockIdx.y, bx = blockIdx.x;

    float *bAr = FRA[w], *bAi = FIA[w];
    float *bBr = FRB[w], *bBi = FIB[w];
    float2* sa2 = (float2*)sacc[w];

    Tw tw0 = twset((float)lane * (1.f/256.f));
    Tw tw1 = twset((float)(lane>>2) * (1.f/64.f));
    Tw tw2 = twset((float)(lane>>4) * (1.f/16.f));
    float twc[4], tws[4], wA[4], wB[4];
#pragma unroll
    for (int c=0;c<4;++c){
        int k = lane + 64*c;
        float x = (float)k * (1.f/512.f);
        twc[c]=cosr(x); tws[c]=sinr(x);
        float2 wv = ((const float2*)win)[k];
        wA[c]=wv.x; wB[c]=wv.y;
    }
#pragma unroll
    for (int j=0;j<8;++j){ int u = lane + 64*j; if (u < WSPAN/2) sa2[u]=make_float2(0.f,0.f); }
    __syncthreads();

    const float* Sb = Sr + (size_t)b*SB;
    const float* magb = mag + ((size_t)b*TFRAMES)*NBINS;
    int t0 = (bx*2 + w)*FPW;

#pragma unroll 1
    for (int fp=0; fp<2; ++fp){
        int tA = t0 + 2*fp, tB = tA + 1;
        float fAr[4], fAi[4], fBr[4], fBi[4];
        load_frame(Sb, wsq, tA, lane, wA, wB, fAr, fAi);
        load_frame(Sb, wsq, tB, lane, wA, wB, fBr, fBi);

        // forward FFTs, interleaved
        fft256_x2<-1>(fAr, fAi, bAr, bAi, fBr, fBi, bBr, bBi, tw0, tw1, tw2, lane);

        // mirror exchange (shared fences)
#pragma unroll
        for (int c=0;c<4;++c){ int u=P(lane+64*c);
            bAr[u]=fAr[c]; bAi[u]=fAi[c]; bBr[u]=fBr[c]; bBi[u]=fBi[c]; }
        wsync();
        float yAr[4], yAi[4], yBr[4], yBi[4];
#pragma unroll
        for (int c=0;c<4;++c){
            int mk = (256 - (lane + 64*c)) & 255;
            int u = P(mk);
            yAr[c]=bAr[u]; yAi[c]=bAi[u]; yBr[c]=bBr[u]; yBi[c]=bBi[u];
        }
        wsync();

        float pAr[4], pAi[4], pBr[4], pBi[4];
        spectral(fAr, fAi, yAr, yAi, magb + (size_t)tA*NBINS, twc, tws, lane, pAr, pAi);
        spectral(fBr, fBi, yBr, yBi, magb + (size_t)tB*NBINS, twc, tws, lane, pBr, pBi);

        // inverse FFTs, interleaved
        fft256_x2<+1>(pAr, pAi, bAr, bAi, pBr, pBi, bBr, bBi, tw0, tw1, tw2, lane);

        // OLA accumulate (sequential — regions overlap)
        constexpr float SC = 1.f/256.f;
        int baseA = (2*fp)*(HOP/2), baseB = (2*fp+1)*(HOP/2);
#pragma unroll
        for (int c=0;c<4;++c){
            int u = baseA + lane + 64*c;
            float2 v = sa2[u];
            v.x += pAr[c]*wA[c]*SC;
            v.y += pAi[c]*wB[c]*SC;
            sa2[u] = v;
        }
        wsync();
#pragma unroll
        for (int c=0;c<4;++c){
            int u = baseB + lane + 64*c;
            float2 v = sa2[u];
            v.x += pBr[c]*wA[c]*SC;
            v.y += pBi[c]*wB[c]*SC;
            sa2[u] = v;
        }
        wsync();
    }
    __syncthreads();
    slot_store(Sw, b, bx, sacc[0], sacc[1], tid);
}

// ============================================================
// k_inv0s: iteration-0 istft from (mag, angles_init) -> slots (legacy path)
// ============================================================
__global__ __launch_bounds__(128,4) void k_inv0s(const float* __restrict__ mag,
                                                 const float* __restrict__ ang,
                                                 const float* __restrict__ win,
                                                 float* __restrict__ Sw){
    __shared__ __align__(16) float sacc[2][WSPAN];
    __shared__ __align__(16) float FR[2][272], FI[2][272];
    int tid = threadIdx.x, w = tid>>6, lane = tid&63;
    int b = blockIdx.y, bx = blockIdx.x;

    float *br = FR[w], *bi = FI[w];
    float2* sa2 = (float2*)sacc[w];

    Tw tw0 = twset((float)lane * (1.f/256.f));
    Tw tw1 = twset((float)(lane>>2) * (1.f/64.f));
    Tw tw2 = twset((float)(lane>>4) * (1.f/16.f));
    float twc[4], tws[4], wA[4], wB[4];
#pragma unroll
    for (int c=0;c<4;++c){
        int k = lane + 64*c;
        float x = (float)k * (1.f/512.f);
        twc[c]=cosr(x); tws[c]=sinr(x);
        float2 wv = ((const float2*)win)[k];
        wA[c]=wv.x; wB[c]=wv.y;
    }
#pragma unroll
    for (int j=0;j<8;++j){ int u = lane + 64*j; if (u < WSPAN/2) sa2[u]=make_float2(0.f,0.f); }
    __syncthreads();

    const float* magb = mag + ((size_t)b*TFRAMES)*NBINS;
    const float* angb = ang + ((size_t)b*TFRAMES)*NBINS;
    int t0 = (bx*2 + w)*FPW;

#pragma unroll 1
    for (int f=0; f<FPW; ++f){
        int t = t0 + f;
        const float* magp = magb + (size_t)t*NBINS;
        const float* angp = angb + (size_t)t*NBINS;
        float sr_[4], si_[4];
#pragma unroll
        for (int c=0;c<4;++c){
            int k = lane + 64*c;
            float m = magp[k], a = angp[k];
            float sn, cs;
            sincosf(a, &sn, &cs);
            sr_[c] = m*cs;
            si_[c] = (c==0 && lane==0) ? 0.f : m*sn;
        }
#pragma unroll
        for (int c=0;c<4;++c){ int k=lane+64*c; br[P(k)]=sr_[c]; bi[P(k)]=si_[c]; }
        if (lane==0){
            br[P(256)] = magp[256]*cosf(angp[256]);
            bi[P(256)] = 0.f;
        }
        wsync();
        float pr[4], pi[4];
#pragma unroll
        for (int c=0;c<4;++c){
            int k = lane + 64*c;
            float yr = br[P(256-k)], yi = bi[P(256-k)];
            float Aer = 0.5f*(sr_[c]+yr), Aei = 0.5f*(si_[c]-yi);
            float Er = sr_[c]-yr, Ei = si_[c]+yi;
            float Bor = 0.5f*(twc[c]*Er - tws[c]*Ei);
            float Boi = 0.5f*(twc[c]*Ei + tws[c]*Er);
            pr[c] = Aer - Boi;
            pi[c] = Aei + Bor;
        }
        wsync();
        inv_accum(pr, pi, br, bi, tw0, tw1, tw2, wA, wB, lane, f, sa2);
    }
    __syncthreads();
    slot_store(Sw, b, bx, sacc[0], sacc[1], tid);
}

// ============================================================
__global__ __launch_bounds__(128) void k_out(const float* __restrict__ S,
                                             const float* __restrict__ wsq,
                                             float* __restrict__ out){
    int b = blockIdx.y;
    int idx = blockIdx.x*128 + threadIdx.x;
    if (idx >= LOUT/2) return;
    const float* Sb = S + (size_t)b*SB;
    float2 v = xs2(Sb, wsq, 256 + 2*idx);
    ((float2*)(out + (size_t)b*LOUT))[idx] = v;
}

// ============================================================
extern "C" void kernel_launch(void* const* d_in, const int* in_sizes, int n_in,
                              void* d_out, int out_size, void* d_ws, size_t ws_size,
                              hipStream_t stream) {
    const float* mag  = (const float*)d_in[0];
    const float* ang0 = (const float*)d_in[1];
    const float* win  = (const float*)d_in[2];
    float* ws = (float*)d_ws;
    float* S[2] = { ws, ws + SBUF };
    float* wsqi = ws + 2*SBUF;
    float* outp = (float*)d_out;

    k_init<<<(XPLEN + 255)/256, 256, 0, stream>>>(win, wsqi);

    dim3 g(NBLK, BATCH);
    k_inv0s<<<g, 128, 0, stream>>>(mag, ang0, win, S[0]);
    for (int it = 0; it < NITER; ++it){
        k_gl<<<g, 128, 0, stream>>>(S[it%2], S[(it+1)%2], mag, win, wsqi);
    }
    k_out<<<dim3(640, BATCH), 128, 0, stream>>>(S[NITER%2], wsqi, outp);
}

// Round 10
// 1496.104 us; speedup vs baseline: 2.3691x; 2.3691x over previous
//
#include <hip/hip_runtime.h>
#include <math.h>

#define BATCH 32
#define TFRAMES 1024
#define NBINS 257
#define NFFT 512
#define HOP 160
#define LOUT 163680
#define XPLEN 164192
#define NITER 32
#define FPW 4                        // frames per wave
#define WSTRIDE (FPW*HOP)            // 640
#define BSTRIDE (2*WSTRIDE)          // 1280 (block = 2 waves = 8 frames)
#define HALO (NFFT-HOP)              // 352
#define WSPAN (WSTRIDE+HALO)         // 992  per-wave OLA span
#define SPAN (BSTRIDE+HALO)          // 1632 per-block OLA span
#define NBLK 128                     // blocks per batch row
#define SLOT SPAN
#define SB ((size_t)NBLK*SLOT)
#define SBUF ((size_t)BATCH*SB)

#define P(i) ((i) + ((i) >> 5))      // LDS pad: 2-way max on stride-1/64 patterns

__device__ __forceinline__ float cosr(float x){ return __builtin_amdgcn_cosf(x); }
__device__ __forceinline__ float sinr(float x){ return __builtin_amdgcn_sinf(x); }
__device__ __forceinline__ void wsync(){
    __builtin_amdgcn_fence(__ATOMIC_SEQ_CST, "wavefront");
    __builtin_amdgcn_wave_barrier();
}
__device__ __forceinline__ float bperm(int addr, float v){
    return __int_as_float(__builtin_amdgcn_ds_bpermute(addr, __float_as_int(v)));
}

struct Tw { float c1,s1,c2,s2,c3,s3; };
__device__ __forceinline__ Tw twset(float x){
    Tw t; float c=cosr(x), s=sinr(x);
    t.c1=c; t.s1=s;
    t.c2=c*c-s*s; t.s2=2.f*c*s;
    t.c3=t.c2*c-t.s2*s; t.s3=t.c2*s+t.s2*c;
    return t;
}

template<int SIGN, bool TWID>
__device__ __forceinline__ void bfly4(const float xr[4], const float xi[4],
                                      const Tw& t, float yr[4], float yi[4]){
    constexpr float SG = (SIGN>0)?1.f:-1.f;
    float apc_r=xr[0]+xr[2], apc_i=xi[0]+xi[2];
    float amc_r=xr[0]-xr[2], amc_i=xi[0]-xi[2];
    float bpd_r=xr[1]+xr[3], bpd_i=xi[1]+xi[3];
    float bmd_r=xr[1]-xr[3], bmd_i=xi[1]-xi[3];
    yr[0]=apc_r+bpd_r; yi[0]=apc_i+bpd_i;
    float u2r=apc_r-bpd_r, u2i=apc_i-bpd_i;
    float u1r=amc_r-SG*bmd_i, u1i=amc_i+SG*bmd_r;
    float u3r=amc_r+SG*bmd_i, u3i=amc_i-SG*bmd_r;
    if (TWID){
        float s1=SG*t.s1, s2=SG*t.s2, s3=SG*t.s3;
        yr[1]=t.c1*u1r-s1*u1i; yi[1]=t.c1*u1i+s1*u1r;
        yr[2]=t.c2*u2r-s2*u2i; yi[2]=t.c2*u2i+s2*u2r;
        yr[3]=t.c3*u3r-s3*u3i; yi[3]=t.c3*u3i+s3*u3r;
    } else {
        yr[1]=u1r; yi[1]=u1i; yr[2]=u2r; yi[2]=u2i; yr[3]=u3r; yi[3]=u3i;
    }
}

// 256-pt complex FFT per wave, radix-4 Stockham, regs in/out, ONE LDS buffer
template<int SIGN>
__device__ __forceinline__ void fft256reg(float xr[4], float xi[4],
                                          float* br, float* bi,
                                          const Tw& tw0, const Tw& tw1, const Tw& tw2,
                                          int lane){
    float yr[4], yi[4], ar[4], ai[4];
    bfly4<SIGN,true>(xr, xi, tw0, yr, yi);
    { int o = 4*lane;
#pragma unroll
      for (int c=0;c<4;++c){ br[P(o+c)]=yr[c]; bi[P(o+c)]=yi[c]; } }
    wsync();
#pragma unroll
    for (int c=0;c<4;++c){ ar[c]=br[P(lane+64*c)]; ai[c]=bi[P(lane+64*c)]; }
    wsync();
    bfly4<SIGN,true>(ar, ai, tw1, yr, yi);
    { int o = (lane&3) + 16*(lane>>2);
#pragma unroll
      for (int c=0;c<4;++c){ br[P(o+4*c)]=yr[c]; bi[P(o+4*c)]=yi[c]; } }
    wsync();
#pragma unroll
    for (int c=0;c<4;++c){ ar[c]=br[P(lane+64*c)]; ai[c]=bi[P(lane+64*c)]; }
    wsync();
    bfly4<SIGN,true>(ar, ai, tw2, yr, yi);
    { int o = (lane&15) + 64*(lane>>4);
#pragma unroll
      for (int c=0;c<4;++c){ br[P(o+16*c)]=yr[c]; bi[P(o+16*c)]=yi[c]; } }
    wsync();
#pragma unroll
    for (int c=0;c<4;++c){ ar[c]=br[P(lane+64*c)]; ai[c]=bi[P(lane+64*c)]; }
    wsync();
    bfly4<SIGN,false>(ar, ai, tw0, xr, xi);
}

// ============================================================
__global__ __launch_bounds__(256) void k_init(const float* __restrict__ win,
                                              float* __restrict__ wsqi){
    int i = blockIdx.x*256 + threadIdx.x;
    if (i < XPLEN){
        int n = i;
        int tmax = n / HOP; if (tmax > TFRAMES-1) tmax = TFRAMES-1;
        int tmin = (n - (NFFT-1) + (HOP-1)) / HOP; if (tmin < 0) tmin = 0;
        float acc = 0.f;
        for (int t = tmin; t <= tmax; ++t){ float w = win[n - t*HOP]; acc += w*w; }
        wsqi[i] = 1.0f / (acc > 1e-11f ? acc : 1.0f);
    }
}

// slot-reconstructed signal reads
__device__ __forceinline__ float xs(const float* __restrict__ Sb,
                                    const float* __restrict__ wsq, int p){
    int bxp = p / BSTRIDE, r = p - bxp*BSTRIDE;
    float a = 0.f;
    if (bxp < NBLK) a = Sb[(size_t)bxp*SLOT + r];
    if (r < HALO && bxp > 0) a += Sb[(size_t)(bxp-1)*SLOT + BSTRIDE + r];
    return a * wsq[p];
}
__device__ __forceinline__ float2 xs2(const float* __restrict__ Sb,
                                      const float* __restrict__ wsq, int p){ // p even
    int bxp = p / BSTRIDE, r = p - bxp*BSTRIDE;
    float2 acc = make_float2(0.f, 0.f);
    if (bxp < NBLK) acc = *(const float2*)(Sb + (size_t)bxp*SLOT + r);
    if (r < HALO && bxp > 0){
        float2 h = *(const float2*)(Sb + (size_t)(bxp-1)*SLOT + BSTRIDE + r);
        acc.x += h.x; acc.y += h.y;
    }
    float2 q = *(const float2*)(wsq + p);
    return make_float2(acc.x*q.x, acc.y*q.y);
}

// inverse tail: pack regs -> inv FFT -> window -> private per-wave sacc
__device__ __forceinline__ void inv_accum(float pr[4], float pi[4],
                                          float* br, float* bi,
                                          const Tw& tw0, const Tw& tw1, const Tw& tw2,
                                          const float wA[4], const float wB[4],
                                          int lane, int f, float2* sa2){
    fft256reg<+1>(pr, pi, br, bi, tw0, tw1, tw2, lane);
    constexpr float SC = 1.f/256.f;
    int base2 = f*(HOP/2);
#pragma unroll
    for (int c=0;c<4;++c){
        int u = base2 + lane + 64*c;
        float2 v = sa2[u];
        v.x += pr[c]*wA[c]*SC;
        v.y += pi[c]*wB[c]*SC;
        sa2[u] = v;
    }
    wsync();
}

__device__ __forceinline__ void slot_store(float* __restrict__ Sw, int b, int bx,
                                           const float* s0, const float* s1, int tid){
    float2* slot2 = (float2*)(Sw + ((size_t)b*NBLK + bx)*SLOT);
    const float2* s0_2 = (const float2*)s0;
    const float2* s1_2 = (const float2*)s1;
#pragma unroll
    for (int j=0;j<7;++j){
        int u = tid + 128*j;
        if (u < SPAN/2){
            float2 v = make_float2(0.f, 0.f);
            if (u < WSPAN/2) v = s0_2[u];
            if (u >= WSTRIDE/2){
                float2 w1 = s1_2[u - WSTRIDE/2];
                v.x += w1.x; v.y += w1.y;
            }
            slot2[u] = v;
        }
    }
}

// frame load (r6-verbatim logic)
__device__ __forceinline__ void load_frame(const float* __restrict__ Sb,
                                           const float* __restrict__ wsq,
                                           int t, int lane,
                                           const float wA[4], const float wB[4],
                                           float fr[4], float fi[4]){
    bool edge = (t < 2) | (t >= TFRAMES-2);
    if (!edge){
        int pb = t*HOP;
#pragma unroll
        for (int c=0;c<4;++c){
            int p = pb + 2*(lane + 64*c);
            float2 v = xs2(Sb, wsq, p);
            fr[c] = v.x*wA[c];
            fi[c] = v.y*wB[c];
        }
    } else {
#pragma unroll
        for (int c=0;c<4;++c){
            int m = lane + 64*c;
            int p0 = t*HOP + 2*m, p1 = p0+1;
            int n0 = (p0<256)?(512-p0):((p0>=LOUT+256)?(2*LOUT+510-p0):p0);
            int n1 = (p1<256)?(512-p1):((p1>=LOUT+256)?(2*LOUT+510-p1):p1);
            fr[c] = xs(Sb, wsq, n0)*wA[c];
            fi[c] = xs(Sb, wsq, n1)*wB[c];
        }
    }
}

// spectral projection (r6-verbatim math)
__device__ __forceinline__ void spectral(const float fr[4], const float fi[4],
                                         const float yr[4], const float yi[4],
                                         const float* __restrict__ magp,
                                         const float twc[4], const float tws[4],
                                         int lane, float pr[4], float pi[4]){
#pragma unroll
    for (int c=0;c<4;++c){
        int k = lane + 64*c;
        float zr = fr[c], zi = fi[c];
        float Xer = 0.5f*(zr+yr[c]), Xei = 0.5f*(zi-yi[c]);
        float Dr = zr-yr[c], Di = zi+yi[c];
        float Xor = 0.5f*Di, Xoi = -0.5f*Dr;
        float Or = twc[c]*Xor + tws[c]*Xoi;
        float Oi = twc[c]*Xoi - tws[c]*Xor;
        float X1r = Xer + Or, X1i = Xei + Oi;
        float X2r = Xer - Or, X2i = Oi - Xei;
        float q1 = X1r*X1r + X1i*X1i;
        bool ok1 = q1 > 1e-30f;
        float v1 = ok1 ? __builtin_amdgcn_rsqf(q1) : 0.f;
        float c1 = ok1 ? X1r*v1 : 1.f, s1 = X1i*v1;
        float q2 = X2r*X2r + X2i*X2i;
        bool ok2 = q2 > 1e-30f;
        float v2 = ok2 ? __builtin_amdgcn_rsqf(q2) : 0.f;
        float c2 = ok2 ? X2r*v2 : 1.f, s2 = X2i*v2;
        float m1 = magp[k], m2 = magp[256-k];
        float S1r = m1*c1, S1i = m1*s1;
        float S2r = m2*c2, S2i = m2*s2;
        float Aer = 0.5f*(S1r+S2r), Aei = 0.5f*(S1i-S2i);
        float Er = S1r - S2r, Ei = S1i + S2i;
        float Bor = 0.5f*(twc[c]*Er - tws[c]*Ei);
        float Boi = 0.5f*(twc[c]*Ei + tws[c]*Er);
        pr[c] = Aer - Boi;
        pi[c] = Aei + Bor;
    }
}

// ============================================================
// k_gl: one Griffin-Lim iteration. block = 2 waves x 4 frames.
// Mirror exchange via ds_bpermute (reg swap c<->3-c + lane 64-l),
// lane0 partners are its own regs (4-c)&3; c=0 self encodes DC/Nyquist.
// ============================================================
__global__ __launch_bounds__(128,4) void k_gl(const float* __restrict__ Sr,
                                              float* __restrict__ Sw,
                                              const float* __restrict__ mag,
                                              const float* __restrict__ win,
                                              const float* __restrict__ wsq){
    __shared__ __align__(16) float sacc[2][WSPAN];
    __shared__ __align__(16) float FR[2][272], FI[2][272];
    int tid = threadIdx.x, w = tid>>6, lane = tid&63;
    int b = blockIdx.y, bx = blockIdx.x;

    float *br = FR[w], *bi = FI[w];
    float2* sa2 = (float2*)sacc[w];

    Tw tw0 = twset((float)lane * (1.f/256.f));
    Tw tw1 = twset((float)(lane>>2) * (1.f/64.f));
    Tw tw2 = twset((float)(lane>>4) * (1.f/16.f));
    float twc[4], tws[4], wA[4], wB[4];
#pragma unroll
    for (int c=0;c<4;++c){
        int k = lane + 64*c;
        float x = (float)k * (1.f/512.f);
        twc[c]=cosr(x); tws[c]=sinr(x);
        float2 wv = ((const float2*)win)[k];
        wA[c]=wv.x; wB[c]=wv.y;
    }
    int am = ((64 - lane) & 63) << 2;    // mirror partner lane address
    bool l0 = (lane == 0);
#pragma unroll
    for (int j=0;j<8;++j){ int u = lane + 64*j; if (u < WSPAN/2) sa2[u]=make_float2(0.f,0.f); }
    __syncthreads();

    const float* Sb = Sr + (size_t)b*SB;
    const float* magb = mag + ((size_t)b*TFRAMES)*NBINS;
    int t0 = (bx*2 + w)*FPW;

#pragma unroll 1
    for (int f=0; f<FPW; ++f){
        int t = t0 + f;
        float fr[4], fi[4];
        load_frame(Sb, wsq, t, lane, wA, wB, fr, fi);

        // forward FFT of packed frame (regs, natural order out)
        fft256reg<-1>(fr, fi, br, bi, tw0, tw1, tw2, lane);

        // mirror via bpermute: y[c] = Z[(256-(lane+64c))&255]
        float yr[4], yi[4];
#pragma unroll
        for (int c=0;c<4;++c){
            float gr = bperm(am, fr[3-c]);
            float gi = bperm(am, fi[3-c]);
            yr[c] = l0 ? fr[(4-c)&3] : gr;
            yi[c] = l0 ? fi[(4-c)&3] : gi;
        }

        float pr[4], pi[4];
        spectral(fr, fi, yr, yi, magb + (size_t)t*NBINS, twc, tws, lane, pr, pi);

        inv_accum(pr, pi, br, bi, tw0, tw1, tw2, wA, wB, lane, f, sa2);
    }
    __syncthreads();
    slot_store(Sw, b, bx, sacc[0], sacc[1], tid);
}

// ============================================================
// k_inv0s: iteration-0 istft from (mag, angles_init) -> slots (legacy path)
// ============================================================
__global__ __launch_bounds__(128,4) void k_inv0s(const float* __restrict__ mag,
                                                 const float* __restrict__ ang,
                                                 const float* __restrict__ win,
                                                 float* __restrict__ Sw){
    __shared__ __align__(16) float sacc[2][WSPAN];
    __shared__ __align__(16) float FR[2][272], FI[2][272];
    int tid = threadIdx.x, w = tid>>6, lane = tid&63;
    int b = blockIdx.y, bx = blockIdx.x;

    float *br = FR[w], *bi = FI[w];
    float2* sa2 = (float2*)sacc[w];

    Tw tw0 = twset((float)lane * (1.f/256.f));
    Tw tw1 = twset((float)(lane>>2) * (1.f/64.f));
    Tw tw2 = twset((float)(lane>>4) * (1.f/16.f));
    float twc[4], tws[4], wA[4], wB[4];
#pragma unroll
    for (int c=0;c<4;++c){
        int k = lane + 64*c;
        float x = (float)k * (1.f/512.f);
        twc[c]=cosr(x); tws[c]=sinr(x);
        float2 wv = ((const float2*)win)[k];
        wA[c]=wv.x; wB[c]=wv.y;
    }
#pragma unroll
    for (int j=0;j<8;++j){ int u = lane + 64*j; if (u < WSPAN/2) sa2[u]=make_float2(0.f,0.f); }
    __syncthreads();

    const float* magb = mag + ((size_t)b*TFRAMES)*NBINS;
    const float* angb = ang + ((size_t)b*TFRAMES)*NBINS;
    int t0 = (bx*2 + w)*FPW;

#pragma unroll 1
    for (int f=0; f<FPW; ++f){
        int t = t0 + f;
        const float* magp = magb + (size_t)t*NBINS;
        const float* angp = angb + (size_t)t*NBINS;
        float sr_[4], si_[4];
#pragma unroll
        for (int c=0;c<4;++c){
            int k = lane + 64*c;
            float m = magp[k], a = angp[k];
            float sn, cs;
            sincosf(a, &sn, &cs);
            sr_[c] = m*cs;
            si_[c] = (c==0 && lane==0) ? 0.f : m*sn;
        }
#pragma unroll
        for (int c=0;c<4;++c){ int k=lane+64*c; br[P(k)]=sr_[c]; bi[P(k)]=si_[c]; }
        if (lane==0){
            br[P(256)] = magp[256]*cosf(angp[256]);
            bi[P(256)] = 0.f;
        }
        wsync();
        float pr[4], pi[4];
#pragma unroll
        for (int c=0;c<4;++c){
            int k = lane + 64*c;
            float yr = br[P(256-k)], yi = bi[P(256-k)];
            float Aer = 0.5f*(sr_[c]+yr), Aei = 0.5f*(si_[c]-yi);
            float Er = sr_[c]-yr, Ei = si_[c]+yi;
            float Bor = 0.5f*(twc[c]*Er - tws[c]*Ei);
            float Boi = 0.5f*(twc[c]*Ei + tws[c]*Er);
            pr[c] = Aer - Boi;
            pi[c] = Aei + Bor;
        }
        wsync();
        inv_accum(pr, pi, br, bi, tw0, tw1, tw2, wA, wB, lane, f, sa2);
    }
    __syncthreads();
    slot_store(Sw, b, bx, sacc[0], sacc[1], tid);
}

// ============================================================
__global__ __launch_bounds__(128) void k_out(const float* __restrict__ S,
                                             const float* __restrict__ wsq,
                                             float* __restrict__ out){
    int b = blockIdx.y;
    int idx = blockIdx.x*128 + threadIdx.x;
    if (idx >= LOUT/2) return;
    const float* Sb = S + (size_t)b*SB;
    float2 v = xs2(Sb, wsq, 256 + 2*idx);
    ((float2*)(out + (size_t)b*LOUT))[idx] = v;
}

// ============================================================
extern "C" void kernel_launch(void* const* d_in, const int* in_sizes, int n_in,
                              void* d_out, int out_size, void* d_ws, size_t ws_size,
                              hipStream_t stream) {
    const float* mag  = (const float*)d_in[0];
    const float* ang0 = (const float*)d_in[1];
    const float* win  = (const float*)d_in[2];
    float* ws = (float*)d_ws;
    float* S[2] = { ws, ws + SBUF };
    float* wsqi = ws + 2*SBUF;
    float* outp = (float*)d_out;

    k_init<<<(XPLEN + 255)/256, 256, 0, stream>>>(win, wsqi);

    dim3 g(NBLK, BATCH);
    k_inv0s<<<g, 128, 0, stream>>>(mag, ang0, win, S[0]);
    for (int it = 0; it < NITER; ++it){
        k_gl<<<g, 128, 0, stream>>>(S[it%2], S[(it+1)%2], mag, win, wsqi);
    }
    k_out<<<dim3(640, BATCH), 128, 0, stream>>>(S[NITER%2], wsqi, outp);
}

// Round 11
// 1430.601 us; speedup vs baseline: 2.4775x; 1.0458x over previous
//
#include <hip/hip_runtime.h>
#include <math.h>

#define BATCH 32
#define TFRAMES 1024
#define NBINS 257
#define NFFT 512
#define HOP 160
#define LOUT 163680
#define XPLEN 164192
#define NITER 32
#define FPW 4                        // frames per wave
#define WSTRIDE (FPW*HOP)            // 640
#define BSTRIDE (2*WSTRIDE)          // 1280 (block = 2 waves = 8 frames)
#define HALO (NFFT-HOP)              // 352
#define WSPAN (WSTRIDE+HALO)         // 992  per-wave OLA span
#define SPAN (BSTRIDE+HALO)          // 1632 per-block OLA span
#define NBLK 128                     // blocks per batch row
#define SLOT SPAN
#define SB ((size_t)NBLK*SLOT)
#define SBUF ((size_t)BATCH*SB)

#define P2(i) ((i) + ((i) >> 4))     // float2-index pad: breaks 16-way aliasing

__device__ __forceinline__ float cosr(float x){ return __builtin_amdgcn_cosf(x); }
__device__ __forceinline__ float sinr(float x){ return __builtin_amdgcn_sinf(x); }
__device__ __forceinline__ void wsync(){
    __builtin_amdgcn_fence(__ATOMIC_SEQ_CST, "wavefront");
    __builtin_amdgcn_wave_barrier();
}
__device__ __forceinline__ float bperm(int addr, float v){
    return __int_as_float(__builtin_amdgcn_ds_bpermute(addr, __float_as_int(v)));
}

struct Tw { float c1,s1,c2,s2,c3,s3; };
__device__ __forceinline__ Tw twset(float x){
    Tw t; float c=cosr(x), s=sinr(x);
    t.c1=c; t.s1=s;
    t.c2=c*c-s*s; t.s2=2.f*c*s;
    t.c3=t.c2*c-t.s2*s; t.s3=t.c2*s+t.s2*c;
    return t;
}

template<int SIGN, bool TWID>
__device__ __forceinline__ void bfly4(const float xr[4], const float xi[4],
                                      const Tw& t, float yr[4], float yi[4]){
    constexpr float SG = (SIGN>0)?1.f:-1.f;
    float apc_r=xr[0]+xr[2], apc_i=xi[0]+xi[2];
    float amc_r=xr[0]-xr[2], amc_i=xi[0]-xi[2];
    float bpd_r=xr[1]+xr[3], bpd_i=xi[1]+xi[3];
    float bmd_r=xr[1]-xr[3], bmd_i=xi[1]-xi[3];
    yr[0]=apc_r+bpd_r; yi[0]=apc_i+bpd_i;
    float u2r=apc_r-bpd_r, u2i=apc_i-bpd_i;
    float u1r=amc_r-SG*bmd_i, u1i=amc_i+SG*bmd_r;
    float u3r=amc_r+SG*bmd_i, u3i=amc_i-SG*bmd_r;
    if (TWID){
        float s1=SG*t.s1, s2=SG*t.s2, s3=SG*t.s3;
        yr[1]=t.c1*u1r-s1*u1i; yi[1]=t.c1*u1i+s1*u1r;
        yr[2]=t.c2*u2r-s2*u2i; yi[2]=t.c2*u2i+s2*u2r;
        yr[3]=t.c3*u3r-s3*u3i; yi[3]=t.c3*u3i+s3*u3r;
    } else {
        yr[1]=u1r; yi[1]=u1i; yr[2]=u2r; yi[2]=u2i; yr[3]=u3r; yi[3]=u3i;
    }
}

// 256-pt complex FFT per wave, radix-4 Stockham, regs in/out.
// ONE float2 LDS buffer: b64 exchanges (half the DS ops of split re/im).
template<int SIGN>
__device__ __forceinline__ void fft256reg(float xr[4], float xi[4],
                                          float2* __restrict__ bz,
                                          const Tw& tw0, const Tw& tw1, const Tw& tw2,
                                          int lane){
    float yr[4], yi[4], ar[4], ai[4];
    bfly4<SIGN,true>(xr, xi, tw0, yr, yi);
    { int o = 4*lane;
#pragma unroll
      for (int c=0;c<4;++c) bz[P2(o+c)] = make_float2(yr[c], yi[c]); }
    wsync();
#pragma unroll
    for (int c=0;c<4;++c){ float2 v = bz[P2(lane+64*c)]; ar[c]=v.x; ai[c]=v.y; }
    wsync();
    bfly4<SIGN,true>(ar, ai, tw1, yr, yi);
    { int o = (lane&3) + 16*(lane>>2);
#pragma unroll
      for (int c=0;c<4;++c) bz[P2(o+4*c)] = make_float2(yr[c], yi[c]); }
    wsync();
#pragma unroll
    for (int c=0;c<4;++c){ float2 v = bz[P2(lane+64*c)]; ar[c]=v.x; ai[c]=v.y; }
    wsync();
    bfly4<SIGN,true>(ar, ai, tw2, yr, yi);
    { int o = (lane&15) + 64*(lane>>4);
#pragma unroll
      for (int c=0;c<4;++c) bz[P2(o+16*c)] = make_float2(yr[c], yi[c]); }
    wsync();
#pragma unroll
    for (int c=0;c<4;++c){ float2 v = bz[P2(lane+64*c)]; ar[c]=v.x; ai[c]=v.y; }
    wsync();
    bfly4<SIGN,false>(ar, ai, tw0, xr, xi);
}

// ============================================================
__global__ __launch_bounds__(256) void k_init(const float* __restrict__ win,
                                              float* __restrict__ wsqi){
    int i = blockIdx.x*256 + threadIdx.x;
    if (i < XPLEN){
        int n = i;
        int tmax = n / HOP; if (tmax > TFRAMES-1) tmax = TFRAMES-1;
        int tmin = (n - (NFFT-1) + (HOP-1)) / HOP; if (tmin < 0) tmin = 0;
        float acc = 0.f;
        for (int t = tmin; t <= tmax; ++t){ float w = win[n - t*HOP]; acc += w*w; }
        wsqi[i] = 1.0f / (acc > 1e-11f ? acc : 1.0f);
    }
}

// slot-reconstructed signal reads
__device__ __forceinline__ float xs(const float* __restrict__ Sb,
                                    const float* __restrict__ wsq, int p){
    int bxp = p / BSTRIDE, r = p - bxp*BSTRIDE;
    float a = 0.f;
    if (bxp < NBLK) a = Sb[(size_t)bxp*SLOT + r];
    if (r < HALO && bxp > 0) a += Sb[(size_t)(bxp-1)*SLOT + BSTRIDE + r];
    return a * wsq[p];
}
__device__ __forceinline__ float2 xs2(const float* __restrict__ Sb,
                                      const float* __restrict__ wsq, int p){ // p even
    int bxp = p / BSTRIDE, r = p - bxp*BSTRIDE;
    float2 acc = make_float2(0.f, 0.f);
    if (bxp < NBLK) acc = *(const float2*)(Sb + (size_t)bxp*SLOT + r);
    if (r < HALO && bxp > 0){
        float2 h = *(const float2*)(Sb + (size_t)(bxp-1)*SLOT + BSTRIDE + r);
        acc.x += h.x; acc.y += h.y;
    }
    float2 q = *(const float2*)(wsq + p);
    return make_float2(acc.x*q.x, acc.y*q.y);
}

// inverse tail: pack regs -> inv FFT -> window -> private per-wave sacc
__device__ __forceinline__ void inv_accum(float pr[4], float pi[4],
                                          float2* __restrict__ bz,
                                          const Tw& tw0, const Tw& tw1, const Tw& tw2,
                                          const float wA[4], const float wB[4],
                                          int lane, int f, float2* sa2){
    fft256reg<+1>(pr, pi, bz, tw0, tw1, tw2, lane);
    constexpr float SC = 1.f/256.f;
    int base2 = f*(HOP/2);
#pragma unroll
    for (int c=0;c<4;++c){
        int u = base2 + lane + 64*c;
        float2 v = sa2[u];
        v.x += pr[c]*wA[c]*SC;
        v.y += pi[c]*wB[c]*SC;
        sa2[u] = v;
    }
    wsync();
}

__device__ __forceinline__ void slot_store(float* __restrict__ Sw, int b, int bx,
                                           const float* s0, const float* s1, int tid){
    float2* slot2 = (float2*)(Sw + ((size_t)b*NBLK + bx)*SLOT);
    const float2* s0_2 = (const float2*)s0;
    const float2* s1_2 = (const float2*)s1;
#pragma unroll
    for (int j=0;j<7;++j){
        int u = tid + 128*j;
        if (u < SPAN/2){
            float2 v = make_float2(0.f, 0.f);
            if (u < WSPAN/2) v = s0_2[u];
            if (u >= WSTRIDE/2){
                float2 w1 = s1_2[u - WSTRIDE/2];
                v.x += w1.x; v.y += w1.y;
            }
            slot2[u] = v;
        }
    }
}

// frame load (r6-verbatim logic)
__device__ __forceinline__ void load_frame(const float* __restrict__ Sb,
                                           const float* __restrict__ wsq,
                                           int t, int lane,
                                           const float wA[4], const float wB[4],
                                           float fr[4], float fi[4]){
    bool edge = (t < 2) | (t >= TFRAMES-2);
    if (!edge){
        int pb = t*HOP;
#pragma unroll
        for (int c=0;c<4;++c){
            int p = pb + 2*(lane + 64*c);
            float2 v = xs2(Sb, wsq, p);
            fr[c] = v.x*wA[c];
            fi[c] = v.y*wB[c];
        }
    } else {
#pragma unroll
        for (int c=0;c<4;++c){
            int m = lane + 64*c;
            int p0 = t*HOP + 2*m, p1 = p0+1;
            int n0 = (p0<256)?(512-p0):((p0>=LOUT+256)?(2*LOUT+510-p0):p0);
            int n1 = (p1<256)?(512-p1):((p1>=LOUT+256)?(2*LOUT+510-p1):p1);
            fr[c] = xs(Sb, wsq, n0)*wA[c];
            fi[c] = xs(Sb, wsq, n1)*wB[c];
        }
    }
}

// spectral projection (r6-verbatim math)
__device__ __forceinline__ void spectral(const float fr[4], const float fi[4],
                                         const float yr[4], const float yi[4],
                                         const float* __restrict__ magp,
                                         const float twc[4], const float tws[4],
                                         int lane, float pr[4], float pi[4]){
#pragma unroll
    for (int c=0;c<4;++c){
        int k = lane + 64*c;
        float zr = fr[c], zi = fi[c];
        float Xer = 0.5f*(zr+yr[c]), Xei = 0.5f*(zi-yi[c]);
        float Dr = zr-yr[c], Di = zi+yi[c];
        float Xor = 0.5f*Di, Xoi = -0.5f*Dr;
        float Or = twc[c]*Xor + tws[c]*Xoi;
        float Oi = twc[c]*Xoi - tws[c]*Xor;
        float X1r = Xer + Or, X1i = Xei + Oi;
        float X2r = Xer - Or, X2i = Oi - Xei;
        float q1 = X1r*X1r + X1i*X1i;
        bool ok1 = q1 > 1e-30f;
        float v1 = ok1 ? __builtin_amdgcn_rsqf(q1) : 0.f;
        float c1 = ok1 ? X1r*v1 : 1.f, s1 = X1i*v1;
        float q2 = X2r*X2r + X2i*X2i;
        bool ok2 = q2 > 1e-30f;
        float v2 = ok2 ? __builtin_amdgcn_rsqf(q2) : 0.f;
        float c2 = ok2 ? X2r*v2 : 1.f, s2 = X2i*v2;
        float m1 = magp[k], m2 = magp[256-k];
        float S1r = m1*c1, S1i = m1*s1;
        float S2r = m2*c2, S2i = m2*s2;
        float Aer = 0.5f*(S1r+S2r), Aei = 0.5f*(S1i-S2i);
        float Er = S1r - S2r, Ei = S1i + S2i;
        float Bor = 0.5f*(twc[c]*Er - tws[c]*Ei);
        float Boi = 0.5f*(twc[c]*Ei + tws[c]*Er);
        pr[c] = Aer - Boi;
        pi[c] = Aei + Bor;
    }
}

// ============================================================
// k_gl: one Griffin-Lim iteration. block = 2 waves x 4 frames.
// b64 FFT exchanges; mirror via ds_bpermute (reg swap + lane 64-l).
// ============================================================
__global__ __launch_bounds__(128,4) void k_gl(const float* __restrict__ Sr,
                                              float* __restrict__ Sw,
                                              const float* __restrict__ mag,
                                              const float* __restrict__ win,
                                              const float* __restrict__ wsq){
    __shared__ __align__(16) float sacc[2][WSPAN];
    __shared__ __align__(16) float2 BZ[2][274];
    int tid = threadIdx.x, w = tid>>6, lane = tid&63;
    int b = blockIdx.y, bx = blockIdx.x;

    float2* bz = BZ[w];
    float2* sa2 = (float2*)sacc[w];

    Tw tw0 = twset((float)lane * (1.f/256.f));
    Tw tw1 = twset((float)(lane>>2) * (1.f/64.f));
    Tw tw2 = twset((float)(lane>>4) * (1.f/16.f));
    float twc[4], tws[4], wA[4], wB[4];
#pragma unroll
    for (int c=0;c<4;++c){
        int k = lane + 64*c;
        float x = (float)k * (1.f/512.f);
        twc[c]=cosr(x); tws[c]=sinr(x);
        float2 wv = ((const float2*)win)[k];
        wA[c]=wv.x; wB[c]=wv.y;
    }
    int am = ((64 - lane) & 63) << 2;    // mirror partner lane address
    bool l0 = (lane == 0);
#pragma unroll
    for (int j=0;j<8;++j){ int u = lane + 64*j; if (u < WSPAN/2) sa2[u]=make_float2(0.f,0.f); }
    __syncthreads();

    const float* Sb = Sr + (size_t)b*SB;
    const float* magb = mag + ((size_t)b*TFRAMES)*NBINS;
    int t0 = (bx*2 + w)*FPW;

#pragma unroll 1
    for (int f=0; f<FPW; ++f){
        int t = t0 + f;
        float fr[4], fi[4];
        load_frame(Sb, wsq, t, lane, wA, wB, fr, fi);

        // forward FFT of packed frame (regs, natural order out)
        fft256reg<-1>(fr, fi, bz, tw0, tw1, tw2, lane);

        // mirror via bpermute: y[c] = Z[(256-(lane+64c))&255]
        float yr[4], yi[4];
#pragma unroll
        for (int c=0;c<4;++c){
            float gr = bperm(am, fr[3-c]);
            float gi = bperm(am, fi[3-c]);
            yr[c] = l0 ? fr[(4-c)&3] : gr;
            yi[c] = l0 ? fi[(4-c)&3] : gi;
        }

        float pr[4], pi[4];
        spectral(fr, fi, yr, yi, magb + (size_t)t*NBINS, twc, tws, lane, pr, pi);

        inv_accum(pr, pi, bz, tw0, tw1, tw2, wA, wB, lane, f, sa2);
    }
    __syncthreads();
    slot_store(Sw, b, bx, sacc[0], sacc[1], tid);
}

// ============================================================
// k_inv0s: iteration-0 istft from (mag, angles_init) -> slots
// ============================================================
__global__ __launch_bounds__(128,4) void k_inv0s(const float* __restrict__ mag,
                                                 const float* __restrict__ ang,
                                                 const float* __restrict__ win,
                                                 float* __restrict__ Sw){
    __shared__ __align__(16) float sacc[2][WSPAN];
    __shared__ __align__(16) float2 BZ[2][274];
    int tid = threadIdx.x, w = tid>>6, lane = tid&63;
    int b = blockIdx.y, bx = blockIdx.x;

    float2* bz = BZ[w];
    float2* sa2 = (float2*)sacc[w];

    Tw tw0 = twset((float)lane * (1.f/256.f));
    Tw tw1 = twset((float)(lane>>2) * (1.f/64.f));
    Tw tw2 = twset((float)(lane>>4) * (1.f/16.f));
    float twc[4], tws[4], wA[4], wB[4];
#pragma unroll
    for (int c=0;c<4;++c){
        int k = lane + 64*c;
        float x = (float)k * (1.f/512.f);
        twc[c]=cosr(x); tws[c]=sinr(x);
        float2 wv = ((const float2*)win)[k];
        wA[c]=wv.x; wB[c]=wv.y;
    }
#pragma unroll
    for (int j=0;j<8;++j){ int u = lane + 64*j; if (u < WSPAN/2) sa2[u]=make_float2(0.f,0.f); }
    __syncthreads();

    const float* magb = mag + ((size_t)b*TFRAMES)*NBINS;
    const float* angb = ang + ((size_t)b*TFRAMES)*NBINS;
    int t0 = (bx*2 + w)*FPW;

#pragma unroll 1
    for (int f=0; f<FPW; ++f){
        int t = t0 + f;
        const float* magp = magb + (size_t)t*NBINS;
        const float* angp = angb + (size_t)t*NBINS;
        float sr_[4], si_[4];
#pragma unroll
        for (int c=0;c<4;++c){
            int k = lane + 64*c;
            float m = magp[k], a = angp[k];
            float sn, cs;
            sincosf(a, &sn, &cs);
            sr_[c] = m*cs;
            si_[c] = (c==0 && lane==0) ? 0.f : m*sn;
        }
        // stage S (+Nyquist) for the c2r pack mirror (b64)
#pragma unroll
        for (int c=0;c<4;++c){ int k=lane+64*c; bz[P2(k)] = make_float2(sr_[c], si_[c]); }
        if (lane==0){
            bz[P2(256)] = make_float2(magp[256]*cosf(angp[256]), 0.f);
        }
        wsync();
        float pr[4], pi[4];
#pragma unroll
        for (int c=0;c<4;++c){
            int k = lane + 64*c;
            float2 yv = bz[P2(256-k)];
            float Aer = 0.5f*(sr_[c]+yv.x), Aei = 0.5f*(si_[c]-yv.y);
            float Er = sr_[c]-yv.x, Ei = si_[c]+yv.y;
            float Bor = 0.5f*(twc[c]*Er - tws[c]*Ei);
            float Boi = 0.5f*(twc[c]*Ei + tws[c]*Er);
            pr[c] = Aer - Boi;
            pi[c] = Aei + Bor;
        }
        wsync();
        inv_accum(pr, pi, bz, tw0, tw1, tw2, wA, wB, lane, f, sa2);
    }
    __syncthreads();
    slot_store(Sw, b, bx, sacc[0], sacc[1], tid);
}

// ============================================================
__global__ __launch_bounds__(128) void k_out(const float* __restrict__ S,
                                             const float* __restrict__ wsq,
                                             float* __restrict__ out){
    int b = blockIdx.y;
    int idx = blockIdx.x*128 + threadIdx.x;
    if (idx >= LOUT/2) return;
    const float* Sb = S + (size_t)b*SB;
    float2 v = xs2(Sb, wsq, 256 + 2*idx);
    ((float2*)(out + (size_t)b*LOUT))[idx] = v;
}

// ============================================================
extern "C" void kernel_launch(void* const* d_in, const int* in_sizes, int n_in,
                              void* d_out, int out_size, void* d_ws, size_t ws_size,
                              hipStream_t stream) {
    const float* mag  = (const float*)d_in[0];
    const float* ang0 = (const float*)d_in[1];
    const float* win  = (const float*)d_in[2];
    float* ws = (float*)d_ws;
    float* S[2] = { ws, ws + SBUF };
    float* wsqi = ws + 2*SBUF;
    float* outp = (float*)d_out;

    k_init<<<(XPLEN + 255)/256, 256, 0, stream>>>(win, wsqi);

    dim3 g(NBLK, BATCH);
    k_inv0s<<<g, 128, 0, stream>>>(mag, ang0, win, S[0]);
    for (int it = 0; it < NITER; ++it){
        k_gl<<<g, 128, 0, stream>>>(S[it%2], S[(it+1)%2], mag, win, wsqi);
    }
    k_out<<<dim3(640, BATCH), 128, 0, stream>>>(S[NITER%2], wsqi, outp);
}